// Round 6
// baseline (498.360 us; speedup 1.0000x reference)
//
#include <hip/hip_runtime.h>

// Problem constants
#define NIMG 32
#define H 112
#define W 112
#define CI 64
#define CO 128
#define ROWS 4            // output rows per block
#define GPI 28            // row-groups per image (112/4)
// K = 3*3*64 = 576 -> 9 K-steps of 64 (i8 MFMA), CI==64 fits one step per tap

typedef __attribute__((ext_vector_type(8))) __bf16 bf16x8;
typedef __attribute__((ext_vector_type(4))) float f32x4;
typedef __attribute__((ext_vector_type(4))) short short4v;
typedef __attribute__((ext_vector_type(4))) int int4v;

// ---- fixed-point quantizers ----
__device__ __forceinline__ short q8bits(float v) {        // bf16-int (fallback path)
    float t = rintf(v * 128.0f);              // round-half-even == np.round
    t = fminf(fmaxf(t, -128.0f), 127.0f);
    union { float f; unsigned u; } cv; cv.f = t;
    return (short)(cv.u >> 16);
}
__device__ __forceinline__ int q8i(float v) {             // int in [-128,127]
    float t = rintf(v * 128.0f);
    t = fminf(fmaxf(t, -128.0f), 127.0f);
    return (int)t;
}

// ---------------- i8 weight pack (verified exact in R2) ----------------
// bp[((kk*8 + nt)*64 + l)*16 + j] = q(w[(kk*64 + (l>>4)*16 + j)*128 + nt*16 + (l&15)])
__global__ __launch_bounds__(256) void quant_pack_w_i8(const float* __restrict__ w,
                                                       signed char* __restrict__ bp) {
    int idx = blockIdx.x * 256 + threadIdx.x;   // grid sized exactly 73728
    int j  = idx & 15;
    int l  = (idx >> 4) & 63;
    int nt = (idx >> 10) & 7;
    int kk = idx >> 13;
    int k = kk * 64 + (l >> 4) * 16 + j;
    int n = nt * 16 + (l & 15);
    bp[idx] = (signed char)q8i(w[k * CO + n]);
}

// ---------------- Fused conv (i8, ring-walk, swizzled LDS) ----------------
// R5 post-mortem: VGPR=84 + FETCH/WRITE inflated ~260MB = breg[9][2] (72 VGPR,
// block-lifetime) spilled to scratch and was reloaded in the inner loop.
// R6 fix: NO breg array -- B fragments loaded inline per kk (short live range,
// L2-resident, barriers bound the scheduling region). acc 56 + pv 28 + ~45
// misc < 170 cap -> no spill.
// Block = 4 output rows of one image. 4 waves; wave w = 112 m x 32 co (co = w*32).
// LDS ring: 4 row slots x 114 cols x 64B, slot(hr) = (hr+1)&3 (h0 % 4 == 0).
// XOR swizzle within each 64B column: phys 16B-group = ci16 ^ (col&3).
// Per step t: load fp32 row h0+t+2 to regs EARLY -> compute row h0+t ->
// quantize+ds_write the prefetched row -> store output row -> barrier (T14).
#define RB 7296   // 114*64 bytes per row slot; multiple of 128 -> bank-neutral

__global__ __launch_bounds__(256, 3) void conv_fused(const float* __restrict__ x,
                                                     const signed char* __restrict__ bp,
                                                     float* __restrict__ out) {
    __shared__ __align__(16) signed char xs[4 * RB];   // 29184 B -> 3 blocks/CU
    int bid0 = blockIdx.x;
    int bid = (bid0 & 7) * 112 + (bid0 >> 3);          // XCD swizzle, 896 = 8*112
    int n  = bid / GPI;
    int rg = bid - n * GPI;
    int h0 = rg * ROWS;
    int tid  = threadIdx.x;
    int lane = tid & 63;
    int wave = tid >> 6;
    int lane15 = lane & 15;
    int hi     = lane >> 4;                   // 0..3 -> logical ci group
    int nt0    = wave * 2;
    const int4v* bp4 = (const int4v*)bp;

    // ---- zero halo cols 0 & 113 of ALL 4 slots (never touched by stage) ----
    if (tid < 32)
        *(int4v*)&xs[(tid >> 3) * RB + ((tid & 4) ? 113 : 0) * 64 + (tid & 3) * 16] =
            (int4v){0, 0, 0, 0};

    // ---- prologue: stage input rows h0-1, h0, h0+1 -> slots 0,1,2 ----
    #pragma unroll
    for (int r = 0; r < 3; ++r) {
        int hr = h0 - 1 + r;
        signed char* dst = &xs[((hr + 1) & 3) * RB];
        if ((unsigned)hr < (unsigned)H) {
            const float* src = x + ((size_t)(n * H + hr) * W) * CI;
            float4 v[7];
            #pragma unroll
            for (int k = 0; k < 7; ++k) v[k] = *(const float4*)&src[k * 1024 + tid * 4];
            #pragma unroll
            for (int k = 0; k < 7; ++k) {
                int b = (q8i(v[k].x) & 255) | ((q8i(v[k].y) & 255) << 8) |
                        ((q8i(v[k].z) & 255) << 16) | (q8i(v[k].w) << 24);
                int L = k * 1024 + tid * 4;
                int col = 1 + (L >> 6);
                int ci  = L & 63;
                *(int*)&dst[col * 64 + (((ci >> 4) ^ (col & 3)) << 4) + (ci & 15)] = b;
            }
        } else {                               // row -1: zeros
            #pragma unroll
            for (int k = 0; k < 7; ++k) {
                int L = k * 1024 + tid * 4;
                int col = 1 + (L >> 6);
                int ci  = L & 63;
                *(int*)&dst[col * 64 + (((ci >> 4) ^ (col & 3)) << 4) + (ci & 15)] = 0;
            }
        }
    }
    __syncthreads();

    // ---- walk 4 output rows ----
    for (int t = 0; t < ROWS; ++t) {
        // early prefetch loads for input row h0+t+2 (slot (t+3)&3)
        float4 pv[7];
        int hpre = h0 + t + 2;
        bool do_pre = (t < ROWS - 1);
        bool pre_valid = do_pre && (hpre < H);
        const float* psrc = x + ((size_t)(n * H + hpre) * W) * CI;
        if (pre_valid) {
            #pragma unroll
            for (int k = 0; k < 5; ++k) pv[k] = *(const float4*)&psrc[k * 1024 + tid * 4];
        }

        // compute output row h0+t from slots (t..t+2)&3
        // B fragments loaded inline per kk (NOT pre-staged: R5 spill lesson)
        int4v acc[7][2];
        #pragma unroll
        for (int mt = 0; mt < 7; ++mt) {
            acc[mt][0] = (int4v){0, 0, 0, 0};
            acc[mt][1] = (int4v){0, 0, 0, 0};
        }
        #pragma unroll
        for (int r = 0; r < 3; ++r) {
            int sbase = ((t + r) & 3) * RB;
            #pragma unroll
            for (int s = 0; s < 3; ++s) {
                int kk = r * 3 + s;
                int4v b0 = bp4[(kk * 8 + nt0    ) * 64 + lane];
                int4v b1 = bp4[(kk * 8 + nt0 + 1) * 64 + lane];
                int col = s + lane15;          // mt adds 16 (== 0 mod 4)
                int abase = sbase + col * 64 + ((hi ^ (col & 3)) << 4);
                #pragma unroll
                for (int mt = 0; mt < 7; ++mt) {
                    int4v a = *(const int4v*)&xs[abase + mt * 1024];
                    acc[mt][0] = __builtin_amdgcn_mfma_i32_16x16x64_i8(a, b0, acc[mt][0], 0, 0, 0);
                    acc[mt][1] = __builtin_amdgcn_mfma_i32_16x16x64_i8(a, b1, acc[mt][1], 0, 0, 0);
                }
            }
        }

        // late prefetch loads + quantize + LDS write (slot (t+3)&3)
        if (pre_valid) {
            #pragma unroll
            for (int k = 5; k < 7; ++k) pv[k] = *(const float4*)&psrc[k * 1024 + tid * 4];
        }
        if (do_pre) {
            signed char* dst = &xs[((t + 3) & 3) * RB];
            #pragma unroll
            for (int k = 0; k < 7; ++k) {
                int b = 0;
                if (pre_valid)
                    b = (q8i(pv[k].x) & 255) | ((q8i(pv[k].y) & 255) << 8) |
                        ((q8i(pv[k].z) & 255) << 16) | (q8i(pv[k].w) << 24);
                int L = k * 1024 + tid * 4;
                int col = 1 + (L >> 6);
                int ci  = L & 63;
                *(int*)&dst[col * 64 + (((ci >> 4) ^ (col & 3)) << 4) + (ci & 15)] = b;
            }
        }

        // epilogue: out = floor(S/128)/128, exact in int
        float* orow = out + (size_t)((n * H + h0 + t) * W) * CO;
        int co0  = wave * 32 + lane15;
        int rowb = hi * 4;
        #pragma unroll
        for (int mt = 0; mt < 7; ++mt)
            #pragma unroll
            for (int tt = 0; tt < 2; ++tt)
                #pragma unroll
                for (int rgi = 0; rgi < 4; ++rgi) {
                    int m = mt * 16 + rowb + rgi;
                    orow[m * CO + co0 + tt * 16] =
                        (float)(acc[mt][tt][rgi] >> 7) * 0.0078125f;
                }

        if (t < ROWS - 1) __syncthreads();
    }
}

// ---------------- bf16 weight pack (fallback path only) ----------------
__global__ __launch_bounds__(256) void quant_pack_w(const float* __restrict__ w,
                                                    short* __restrict__ bp) {
    int idx = blockIdx.x * 256 + threadIdx.x;   // grid sized exactly 73728
    int j    = idx & 7;
    int lane = (idx >> 3) & 63;
    int nt   = (idx >> 9) & 7;
    int kt   = idx >> 12;
    int k = kt * 32 + (lane >> 4) * 8 + j;
    int n = nt * 16 + (lane & 15);
    bp[idx] = q8bits(w[k * CO + n]);
}

// ---------------- R1 fallback (tiny ws): verified exact ----------------
#define LDSW 114
#define LDST 72
__global__ __launch_bounds__(256, 3) void conv_fb(const float* __restrict__ x,
                                                  const short* __restrict__ bp,
                                                  float* __restrict__ out) {
    __shared__ short xs[3 * LDSW * LDST];
    int bid = blockIdx.x;
    int n = bid / H;
    int h = bid - n * H;
    int tid = threadIdx.x;
    const float* xin = x + (size_t)n * (H * W * CI);
    for (int r = 0; r < 3; ++r) {
        int hrow = h + r - 1;
        bool rowok = ((unsigned)hrow < (unsigned)H);
        const float* srow = xin + (size_t)hrow * (W * CI);
        for (int t = tid; t < LDSW * 16; t += 256) {
            int c = t >> 4;
            int ci4 = (t & 15) << 2;
            int wcol = c - 1;
            float4 v = {0.f, 0.f, 0.f, 0.f};
            if (rowok && (unsigned)wcol < (unsigned)W)
                v = *(const float4*)&srow[wcol * CI + ci4];
            short4v sv;
            sv.x = q8bits(v.x); sv.y = q8bits(v.y);
            sv.z = q8bits(v.z); sv.w = q8bits(v.w);
            *(short4v*)&xs[(r * LDSW + c) * LDST + ci4] = sv;
        }
    }
    __syncthreads();
    int lane = tid & 63;
    int wave = tid >> 6;
    int laneoff = (lane & 15) * LDST + (lane >> 4) * 8;
    const bf16x8* bfr = (const bf16x8*)bp;
    int nt0 = wave * 2;
    f32x4 acc[7][2];
    #pragma unroll
    for (int mt = 0; mt < 7; ++mt) {
        acc[mt][0] = (f32x4){0.f, 0.f, 0.f, 0.f};
        acc[mt][1] = (f32x4){0.f, 0.f, 0.f, 0.f};
    }
    #pragma unroll
    for (int kk = 0; kk < 18; ++kk) {
        int rs = kk >> 1;
        int r = rs / 3;
        int s = rs - r * 3;
        bf16x8 b0 = bfr[(kk * 8 + nt0    ) * 64 + lane];
        bf16x8 b1 = bfr[(kk * 8 + nt0 + 1) * 64 + lane];
        int abase = (r * LDSW + s) * LDST + (kk & 1) * 32 + laneoff;
        #pragma unroll
        for (int mt = 0; mt < 7; ++mt) {
            bf16x8 a = *(const bf16x8*)&xs[abase + mt * 16 * LDST];
            acc[mt][0] = __builtin_amdgcn_mfma_f32_16x16x32_bf16(a, b0, acc[mt][0], 0, 0, 0);
            acc[mt][1] = __builtin_amdgcn_mfma_f32_16x16x32_bf16(a, b1, acc[mt][1], 0, 0, 0);
        }
    }
    float* orow = out + (size_t)(n * H + h) * (W * CO);
    int colc = wave * 32 + (lane & 15);
    int rowb = (lane >> 4) * 4;
    #pragma unroll
    for (int mt = 0; mt < 7; ++mt)
        #pragma unroll
        for (int t2 = 0; t2 < 2; ++t2)
            #pragma unroll
            for (int rgi = 0; rgi < 4; ++rgi) {
                int m = mt * 16 + rowb + rgi;
                orow[m * CO + colc + t2 * 16] =
                    floorf(acc[mt][t2][rgi] * 0.0078125f) * 0.0078125f;
            }
}

extern "C" void kernel_launch(void* const* d_in, const int* in_sizes, int n_in,
                              void* d_out, int out_size, void* d_ws, size_t ws_size,
                              hipStream_t stream) {
    const float* x = (const float*)d_in[0];     // (32,112,112,64) fp32 NHWC
    const float* w = (const float*)d_in[1];     // (3,3,64,128) fp32 HWIO
    float* out = (float*)d_out;                 // (32,112,112,128) fp32

    const size_t BPI8_BYTES = 73728;            // 576*128 i8 packed weights

    if (ws_size >= BPI8_BYTES) {
        signed char* bp8 = (signed char*)d_ws;
        quant_pack_w_i8<<<288, 256, 0, stream>>>(w, bp8);
        conv_fused<<<NIMG * GPI, 256, 0, stream>>>(x, bp8, out);   // 896 blocks
    } else {
        short* bp = (short*)d_ws;               // 147456 B bf16 packed weights
        quant_pack_w<<<288, 256, 0, stream>>>(w, bp);
        conv_fb<<<NIMG * H, 256, 0, stream>>>(x, bp, out);
    }
}

// Round 7
// 301.947 us; speedup vs baseline: 1.6505x; 1.6505x over previous
//
#include <hip/hip_runtime.h>

// Problem constants
#define NIMG 32
#define H 112
#define W 112
#define CI 64
#define CO 128
// K = 3*3*64 = 576 -> 9 K-steps of 64 (i8 MFMA), CI==64 fits one step per tap

typedef __attribute__((ext_vector_type(8))) __bf16 bf16x8;
typedef __attribute__((ext_vector_type(4))) float f32x4;
typedef __attribute__((ext_vector_type(4))) short short4v;
typedef __attribute__((ext_vector_type(4))) int int4v;
typedef __attribute__((ext_vector_type(2))) int int2v;

// ---- fixed-point quantizers ----
__device__ __forceinline__ short q8bits(float v) {        // bf16-int (fallback path)
    float t = rintf(v * 128.0f);              // round-half-even == np.round
    t = fminf(fmaxf(t, -128.0f), 127.0f);
    union { float f; unsigned u; } cv; cv.f = t;
    return (short)(cv.u >> 16);
}
__device__ __forceinline__ int q8i(float v) {             // int in [-128,127]
    float t = rintf(v * 128.0f);
    t = fminf(fmaxf(t, -128.0f), 127.0f);
    return (int)t;
}

// ---------------- i8 weight pack (verified exact in R2) ----------------
// bp[((kk*8 + nt)*64 + l)*16 + j] = q(w[(kk*64 + (l>>4)*16 + j)*128 + nt*16 + (l&15)])
__global__ __launch_bounds__(256) void quant_pack_w_i8(const float* __restrict__ w,
                                                       signed char* __restrict__ bp) {
    int idx = blockIdx.x * 256 + threadIdx.x;   // grid sized exactly 73728
    int j  = idx & 15;
    int l  = (idx >> 4) & 63;
    int nt = (idx >> 10) & 7;
    int kk = idx >> 13;
    int k = kk * 64 + (l >> 4) * 16 + j;
    int n = nt * 16 + (l & 15);
    bp[idx] = (signed char)q8i(w[k * CO + n]);
}

// ---------------- activation prepass: fp32 NHWC -> i8 NHWC (verified R2) ----------------
__global__ __launch_bounds__(256) void quant_x_i8(const float* __restrict__ x,
                                                  signed char* __restrict__ xq) {
    size_t i = ((size_t)blockIdx.x * 256 + threadIdx.x) * 8;
    float4 v0 = *(const float4*)&x[i];
    float4 v1 = *(const float4*)&x[i + 4];
    int b0 = (q8i(v0.x) & 255) | ((q8i(v0.y) & 255) << 8) |
             ((q8i(v0.z) & 255) << 16) | (q8i(v0.w) << 24);
    int b1 = (q8i(v1.x) & 255) | ((q8i(v1.y) & 255) << 8) |
             ((q8i(v1.z) & 255) << 16) | (q8i(v1.w) << 24);
    int2v p; p.x = b0; p.y = b1;
    *(int2v*)&xq[i] = p;
}

// ---------------- Main conv (i8): R2 structure, de-pathologized ----------------
// R5/R6 post-mortem: __launch_bounds__(256,3) drove the allocator to an 84-VGPR
// budget (=512/6) regardless of ~130 live values -> massive scratch spill
// (FETCH/WRITE inflated ~200MB, conv 245-300us). R7: NO waves-per-eu hint
// (VGPR budget free up to 256) and NO long-lived breg array (B loaded inline
// per kk; worst-case full hoist = ~160 live < 256 -> no spill either way).
// Structure otherwise identical to R2's verified conv_i8:
// 1 output row per block, 4 waves; wave w = 112 m x 32 co (co = w*32).
// LDS: 3 input rows x 114 cols x 64B i8, linear; DMA interior cols via
// global_load_lds (7 x 1KB chunks per row), halo cols + boundary rows zeroed.
#define RB 7296   // 114*64 bytes per row slot

__global__ __launch_bounds__(256) void conv_i8(const signed char* __restrict__ xq,
                                               const signed char* __restrict__ bp,
                                               float* __restrict__ out) {
    __shared__ __align__(16) signed char xs[3 * RB];   // 21888 B
    int bid0 = blockIdx.x;
    int bid = (bid0 & 7) * 448 + (bid0 >> 3);   // XCD swizzle (3584 % 8 == 0, bijective)
    int n = bid / H;
    int h = bid - n * H;
    int tid  = threadIdx.x;
    int lane = tid & 63;
    int wave = tid >> 6;

    // ---- stage: DMA 3 input rows (7 x 1KB chunks each), split over waves ----
    const signed char* base = xq + (size_t)(n * H) * (W * CI);
    for (int idx = wave; idx < 21; idx += 4) {        // wave-uniform row/i
        int row = idx / 7;
        int i = idx - row * 7;
        int hr = h - 1 + row;
        if ((unsigned)hr < (unsigned)H) {
            const signed char* g = base + (size_t)hr * (W * CI) + i * 1024 + lane * 16;
            __builtin_amdgcn_global_load_lds(
                (const __attribute__((address_space(1))) void*)g,
                (__attribute__((address_space(3))) void*)(xs + row * RB + 64 + i * 1024),
                16, 0, 0);
        }
    }

    // ---- zero boundary rows + halo cols ----
    if (h == 0)
        for (int t = tid; t < 456; t += 256) *(int4v*)&xs[t * 16] = (int4v){0, 0, 0, 0};
    if (h == H - 1)
        for (int t = tid; t < 456; t += 256) *(int4v*)&xs[2 * RB + t * 16] = (int4v){0, 0, 0, 0};
    if (tid < 24) {                           // cols 0 and 113, 3 rows, 64B each
        int r2 = tid >> 3, ci = tid & 7;
        int c = (ci & 4) ? 113 : 0;
        *(int4v*)&xs[r2 * RB + c * 64 + (ci & 3) * 16] = (int4v){0, 0, 0, 0};
    }
    __syncthreads();

    // ---- implicit GEMM: wave = 112 m x 32 co, K=576 in 9 steps of 64 ----
    int lane15 = lane & 15;
    int hi     = lane >> 4;                   // 0..3 -> ci offset hi*16
    int nt0    = wave * 2;
    const int4v* bp4 = (const int4v*)bp;

    int4v acc[7][2];
    #pragma unroll
    for (int mt = 0; mt < 7; ++mt) {
        acc[mt][0] = (int4v){0, 0, 0, 0};
        acc[mt][1] = (int4v){0, 0, 0, 0};
    }

    #pragma unroll
    for (int r = 0; r < 3; ++r) {
        #pragma unroll
        for (int s = 0; s < 3; ++s) {
            int kk = r * 3 + s;
            int4v b0 = bp4[(kk * 8 + nt0    ) * 64 + lane];   // inline: short live range
            int4v b1 = bp4[(kk * 8 + nt0 + 1) * 64 + lane];
            int abase = r * RB + (s + lane15) * 64 + hi * 16;
            #pragma unroll
            for (int mt = 0; mt < 7; ++mt) {
                int4v a = *(const int4v*)&xs[abase + mt * 1024];
                acc[mt][0] = __builtin_amdgcn_mfma_i32_16x16x64_i8(a, b0, acc[mt][0], 0, 0, 0);
                acc[mt][1] = __builtin_amdgcn_mfma_i32_16x16x64_i8(a, b1, acc[mt][1], 0, 0, 0);
            }
        }
    }

    // ---- epilogue: out = floor(S/128)/128, exact in int ----
    float* orow = out + (size_t)((n * H + h) * W) * CO;
    int co0  = wave * 32 + lane15;
    int rowb = hi * 4;
    #pragma unroll
    for (int mt = 0; mt < 7; ++mt)
        #pragma unroll
        for (int t = 0; t < 2; ++t)
            #pragma unroll
            for (int rg = 0; rg < 4; ++rg) {
                int m = mt * 16 + rowb + rg;
                orow[m * CO + co0 + t * 16] =
                    (float)(acc[mt][t][rg] >> 7) * 0.0078125f;
            }
}

// ---------------- bf16 weight pack (fallback path only) ----------------
__global__ __launch_bounds__(256) void quant_pack_w(const float* __restrict__ w,
                                                    short* __restrict__ bp) {
    int idx = blockIdx.x * 256 + threadIdx.x;   // grid sized exactly 73728
    int j    = idx & 7;
    int lane = (idx >> 3) & 63;
    int nt   = (idx >> 9) & 7;
    int kt   = idx >> 12;
    int k = kt * 32 + (lane >> 4) * 8 + j;
    int n = nt * 16 + (lane & 15);
    bp[idx] = q8bits(w[k * CO + n]);
}

// ---------------- R1 fallback (tiny ws): verified exact ----------------
#define LDSW 114
#define LDST 72
__global__ __launch_bounds__(256) void conv_fb(const float* __restrict__ x,
                                               const short* __restrict__ bp,
                                               float* __restrict__ out) {
    __shared__ short xs[3 * LDSW * LDST];
    int bid = blockIdx.x;
    int n = bid / H;
    int h = bid - n * H;
    int tid = threadIdx.x;
    const float* xin = x + (size_t)n * (H * W * CI);
    for (int r = 0; r < 3; ++r) {
        int hrow = h + r - 1;
        bool rowok = ((unsigned)hrow < (unsigned)H);
        const float* srow = xin + (size_t)hrow * (W * CI);
        for (int t = tid; t < LDSW * 16; t += 256) {
            int c = t >> 4;
            int ci4 = (t & 15) << 2;
            int wcol = c - 1;
            float4 v = {0.f, 0.f, 0.f, 0.f};
            if (rowok && (unsigned)wcol < (unsigned)W)
                v = *(const float4*)&srow[wcol * CI + ci4];
            short4v sv;
            sv.x = q8bits(v.x); sv.y = q8bits(v.y);
            sv.z = q8bits(v.z); sv.w = q8bits(v.w);
            *(short4v*)&xs[(r * LDSW + c) * LDST + ci4] = sv;
        }
    }
    __syncthreads();
    int lane = tid & 63;
    int wave = tid >> 6;
    int laneoff = (lane & 15) * LDST + (lane >> 4) * 8;
    const bf16x8* bfr = (const bf16x8*)bp;
    int nt0 = wave * 2;
    f32x4 acc[7][2];
    #pragma unroll
    for (int mt = 0; mt < 7; ++mt) {
        acc[mt][0] = (f32x4){0.f, 0.f, 0.f, 0.f};
        acc[mt][1] = (f32x4){0.f, 0.f, 0.f, 0.f};
    }
    #pragma unroll
    for (int kk = 0; kk < 18; ++kk) {
        int rs = kk >> 1;
        int r = rs / 3;
        int s = rs - r * 3;
        bf16x8 b0 = bfr[(kk * 8 + nt0    ) * 64 + lane];
        bf16x8 b1 = bfr[(kk * 8 + nt0 + 1) * 64 + lane];
        int abase = (r * LDSW + s) * LDST + (kk & 1) * 32 + laneoff;
        #pragma unroll
        for (int mt = 0; mt < 7; ++mt) {
            bf16x8 a = *(const bf16x8*)&xs[abase + mt * 16 * LDST];
            acc[mt][0] = __builtin_amdgcn_mfma_f32_16x16x32_bf16(a, b0, acc[mt][0], 0, 0, 0);
            acc[mt][1] = __builtin_amdgcn_mfma_f32_16x16x32_bf16(a, b1, acc[mt][1], 0, 0, 0);
        }
    }
    float* orow = out + (size_t)(n * H + h) * (W * CO);
    int colc = wave * 32 + (lane & 15);
    int rowb = (lane >> 4) * 4;
    #pragma unroll
    for (int mt = 0; mt < 7; ++mt)
        #pragma unroll
        for (int t2 = 0; t2 < 2; ++t2)
            #pragma unroll
            for (int rg = 0; rg < 4; ++rg) {
                int m = mt * 16 + rowb + rg;
                orow[m * CO + colc + t2 * 16] =
                    floorf(acc[mt][t2][rg] * 0.0078125f) * 0.0078125f;
            }
}

extern "C" void kernel_launch(void* const* d_in, const int* in_sizes, int n_in,
                              void* d_out, int out_size, void* d_ws, size_t ws_size,
                              hipStream_t stream) {
    const float* x = (const float*)d_in[0];     // (32,112,112,64) fp32 NHWC
    const float* w = (const float*)d_in[1];     // (3,3,64,128) fp32 HWIO
    float* out = (float*)d_out;                 // (32,112,112,128) fp32

    const size_t BPI8_BYTES = 73728;            // 576*128 i8 packed weights
    const size_t XQ8_BYTES  = (size_t)NIMG * H * W * CI;   // 25,690,112 B

    if (ws_size >= BPI8_BYTES + XQ8_BYTES) {
        signed char* bp8 = (signed char*)d_ws;
        signed char* xq8 = (signed char*)d_ws + BPI8_BYTES;
        quant_pack_w_i8<<<288, 256, 0, stream>>>(w, bp8);
        quant_x_i8<<<12544, 256, 0, stream>>>(x, xq8);     // 12544*256*8 == 25690112
        conv_i8<<<NIMG * H, 256, 0, stream>>>(xq8, bp8, out);  // 3584 blocks
    } else {
        short* bp = (short*)d_ws;               // 147456 B bf16 packed weights
        quant_pack_w<<<288, 256, 0, stream>>>(w, bp);
        conv_fb<<<NIMG * H, 256, 0, stream>>>(x, bp, out);
    }
}